// Round 9
// baseline (265.801 us; speedup 1.0000x reference)
//
#include <hip/hip_runtime.h>
#include <hip/hip_bf16.h>

#define D128 128
#define NSPLIT 8
#define KT 64
#define SNR 32
#define SKT 128
#define TOPS 8
#define FCAP 16

typedef float4 f4;
typedef __attribute__((ext_vector_type(8))) short short8v;
typedef __attribute__((ext_vector_type(4))) float f32x4;

__device__ __forceinline__ unsigned short f2bu(float x){
  __hip_bfloat16 h = __float2bfloat16(x);
  return *(unsigned short*)&h;
}
__device__ __forceinline__ float bu2f(unsigned short u){
  return __uint_as_float(((unsigned)u) << 16);
}

#define GLDS16(gp, lp) __builtin_amdgcn_global_load_lds( \
    (const __attribute__((address_space(1))) unsigned int*)(const void*)(gp), \
    (__attribute__((address_space(3))) unsigned int*)(lp), 16, 0, 0)

// zero the pot4 accumulator (ws is poisoned 0xAA before every launch)
__global__ __launch_bounds__(256) void k_zero(float* __restrict__ p, int total){
  int i = blockIdx.x*256 + threadIdx.x;
  int stride = gridDim.x*256;
  for(; i < total; i += stride) p[i] = 0.f;
}

// Fused: rfrac = pos/box; transpose + bf16-split k_vector/v_vector into
// [d][atom]; |q| bf16 row-major with chunk-XOR swizzle baked into global layout.
__global__ __launch_bounds__(256) void k_cvt(const float* __restrict__ pos,
    const float* __restrict__ cell, float* __restrict__ rfrac,
    const float* __restrict__ q, const float* __restrict__ kvec,
    const float* __restrict__ vvec, unsigned short* __restrict__ kvhT,
    unsigned short* __restrict__ kvlT, unsigned short* __restrict__ vvhT,
    unsigned short* __restrict__ qa_bf, int N){
  __shared__ float sk[32][132], sv[32][132];
  const int tid = threadIdx.x;
  const int c0 = blockIdx.x*32;
  if(tid < 32){
    int i = c0 + tid;
    float bx = cell[0], by = cell[4], bz = cell[8];
    f4 r; r.x = pos[i*3+0]/bx; r.y = pos[i*3+1]/by; r.z = pos[i*3+2]/bz; r.w = 0.f;
    ((f4*)rfrac)[i] = r;
  }
  #pragma unroll
  for(int i=0;i<2;i++){
    int idx = tid + i*256;            // 512 tasks: 32 rows x 16 chunks
    int row = idx >> 4, c = idx & 15;
    const float* src = q + (size_t)(c0+row)*D128 + c*8;
    f4 v0 = *(const f4*)src, v1 = *(const f4*)(src+4);
    uint4 o;
    o.x = (unsigned)f2bu(fabsf(v0.x)) | ((unsigned)f2bu(fabsf(v0.y))<<16);
    o.y = (unsigned)f2bu(fabsf(v0.z)) | ((unsigned)f2bu(fabsf(v0.w))<<16);
    o.z = (unsigned)f2bu(fabsf(v1.x)) | ((unsigned)f2bu(fabsf(v1.y))<<16);
    o.w = (unsigned)f2bu(fabsf(v1.z)) | ((unsigned)f2bu(fabsf(v1.w))<<16);
    *(uint4*)(qa_bf + (size_t)(c0+row)*D128 + ((c ^ (row&7))<<3)) = o;
  }
  #pragma unroll
  for(int i=0;i<4;i++){
    int idx = tid + i*256;            // 1024 f4-loads: 32 atoms x 32 quads
    int a = idx >> 5, fq = idx & 31;
    f4 v = ((const f4*)(kvec + (size_t)(c0+a)*D128))[fq];
    *(f4*)&sk[a][fq*4] = v;
    f4 u = ((const f4*)(vvec + (size_t)(c0+a)*D128))[fq];
    *(f4*)&sv[a][fq*4] = u;
  }
  __syncthreads();
  #pragma unroll
  for(int i=0;i<4;i++){
    int idx = tid + i*256;            // 1024 quad-items: 128 d x 8 atom-quads
    int d = idx >> 3, aq = idx & 7;
    size_t ob = (size_t)d*N + c0 + aq*4;
    ushort4 h, l, vh;
    float x0 = sk[aq*4+0][d], x1 = sk[aq*4+1][d], x2 = sk[aq*4+2][d], x3 = sk[aq*4+3][d];
    h.x = f2bu(x0); h.y = f2bu(x1); h.z = f2bu(x2); h.w = f2bu(x3);
    l.x = f2bu(x0 - bu2f(h.x)); l.y = f2bu(x1 - bu2f(h.y));
    l.z = f2bu(x2 - bu2f(h.z)); l.w = f2bu(x3 - bu2f(h.w));
    vh.x = f2bu(sv[aq*4+0][d]); vh.y = f2bu(sv[aq*4+1][d]);
    vh.z = f2bu(sv[aq*4+2][d]); vh.w = f2bu(sv[aq*4+3][d]);
    *(ushort4*)(kvhT + ob) = h;
    *(ushort4*)(kvlT + ob) = l;
    *(ushort4*)(vvhT + ob) = vh;
  }
}

// MFMA structure factors. 512 threads / 8 waves = 2 k-waves x 4 d-waves;
// wave tile k32 x d32. Software-pipelined: stage(next) + rfrac-prefetch issued
// BEFORE the MFMA section (latency hidden under it); egen's trig+ds_write run
// AFTER the MFMAs on registers loaded one iteration earlier. Unroll-by-2 keeps
// the rfA/rfB ping-pong statically indexed (no scratch).
__global__ __launch_bounds__(512) void k_pot_mfma(
    const unsigned short* __restrict__ kvhT, const unsigned short* __restrict__ kvlT,
    const unsigned short* __restrict__ vvhT, const float* __restrict__ rfrac,
    const int* __restrict__ kfwd, float* __restrict__ pot4, int N, int K){
  const int tid = threadIdx.x;
  const int k0 = blockIdx.x*KT;
  const int split = blockIdx.y;
  const int part = N/NSPLIT;
  const int abase = split*part;
  __shared__ unsigned short Ae[2][4][KT][32];    // 32 KB
  __shared__ unsigned short Bl[2][3][D128][32];  // 48 KB
  const int w = tid >> 6, l = tid & 63, l15 = l & 15, g = l >> 4;
  const int kbase = (w & 1)*32, dbase = (w >> 1)*32;
  // E-gen mapping: 1 k x 4 atoms per thread (512 threads = 64k x 8 atom-quads)
  const int ke = tid >> 3;           // 0..63 local k
  const int ae0 = (tid & 7)*4;       // atom base
  float kfx, kfy, kfz;
  {
    int kk = min(k0 + ke, K-1);
    kfx = (float)kfwd[3*kk]; kfy = (float)kfwd[3*kk+1]; kfz = (float)kfwd[3*kk+2];
  }
  f32x4 acc[2][2][4];   // [ksub][dsub][kc,ks,vc,vs]
  #pragma unroll
  for(int i=0;i<2;i++)
    #pragma unroll
    for(int j=0;j<2;j++)
      #pragma unroll
      for(int p=0;p<4;p++)
        acc[i][j][p] = (f32x4){0.f,0.f,0.f,0.f};
  const int csrcS = ((l & 3) ^ ((l >> 3) & 3))*8;     // staging source chunk (shorts)
  const int cA    = (g ^ ((l15 >> 1) & 3))*8;         // swizzled read chunk (shorts)

  auto stage = [&](int buf, int c0a){
    int rbase = w*16;
    size_t goff = (size_t)(rbase + (l >> 2))*N + c0a + csrcS;
    GLDS16(kvhT + goff, &Bl[buf][0][rbase][0]);
    GLDS16(kvlT + goff, &Bl[buf][1][rbase][0]);
    GLDS16(vvhT + goff, &Bl[buf][2][rbase][0]);
  };
  auto rfload = [&](f4* dst, int c0a){
    #pragma unroll
    for(int jp=0; jp<4; jp++) dst[jp] = ((const f4*)rfrac)[c0a + ae0 + jp];
  };
  auto egen_from = [&](int buf, const f4* rf){
    unsigned ow0[2], ow1[2], ow2[2], ow3[2];
    #pragma unroll
    for(int jp=0; jp<2; jp++){
      f4 ra = rf[jp*2], rb = rf[jp*2+1];
      float ta = __builtin_amdgcn_fractf(ra.x*kfx + ra.y*kfy + ra.z*kfz);
      float tb = __builtin_amdgcn_fractf(rb.x*kfx + rb.y*kfy + rb.z*kfz);
      float ca = __builtin_amdgcn_cosf(ta), sa = __builtin_amdgcn_sinf(ta);
      float cb = __builtin_amdgcn_cosf(tb), sb = __builtin_amdgcn_sinf(tb);
      unsigned cba = __float_as_uint(ca), cbb = __float_as_uint(cb);
      unsigned sba = __float_as_uint(sa), sbb = __float_as_uint(sb);
      ow0[jp] = (cba >> 16) | (cbb & 0xffff0000u);
      ow2[jp] = (sba >> 16) | (sbb & 0xffff0000u);
      float cla = ca - __uint_as_float(cba & 0xffff0000u);
      float clb = cb - __uint_as_float(cbb & 0xffff0000u);
      float sla = sa - __uint_as_float(sba & 0xffff0000u);
      float slb = sb - __uint_as_float(sbb & 0xffff0000u);
      ow1[jp] = (unsigned)f2bu(cla) | ((unsigned)f2bu(clb) << 16);
      ow3[jp] = (unsigned)f2bu(sla) | ((unsigned)f2bu(slb) << 16);
    }
    int cdst = ((((ae0 >> 3) ^ ((ke >> 1) & 3)) << 3) | (ae0 & 4));  // shorts
    *(uint2*)&Ae[buf][0][ke][cdst] = make_uint2(ow0[0], ow0[1]);
    *(uint2*)&Ae[buf][1][ke][cdst] = make_uint2(ow1[0], ow1[1]);
    *(uint2*)&Ae[buf][2][ke][cdst] = make_uint2(ow2[0], ow2[1]);
    *(uint2*)&Ae[buf][3][ke][cdst] = make_uint2(ow3[0], ow3[1]);
  };
  auto mfma_body = [&](int cur){
    short8v bKh[2], bKl[2], bVh[2];
    #pragma unroll
    for(int ds2=0; ds2<2; ds2++){
      int row = dbase + ds2*16 + l15;
      bKh[ds2] = *(const short8v*)&Bl[cur][0][row][cA];
      bKl[ds2] = *(const short8v*)&Bl[cur][1][row][cA];
      bVh[ds2] = *(const short8v*)&Bl[cur][2][row][cA];
    }
    #pragma unroll
    for(int ks2=0; ks2<2; ks2++){
      int krow = kbase + ks2*16 + l15;
      short8v e0 = *(const short8v*)&Ae[cur][0][krow][cA];
      short8v e1 = *(const short8v*)&Ae[cur][1][krow][cA];
      short8v e2 = *(const short8v*)&Ae[cur][2][krow][cA];
      short8v e3 = *(const short8v*)&Ae[cur][3][krow][cA];
      #pragma unroll
      for(int ds2=0; ds2<2; ds2++){
        acc[ks2][ds2][0] = __builtin_amdgcn_mfma_f32_16x16x32_bf16(e0, bKh[ds2], acc[ks2][ds2][0], 0,0,0);
        acc[ks2][ds2][1] = __builtin_amdgcn_mfma_f32_16x16x32_bf16(e2, bKh[ds2], acc[ks2][ds2][1], 0,0,0);
        acc[ks2][ds2][2] = __builtin_amdgcn_mfma_f32_16x16x32_bf16(e0, bVh[ds2], acc[ks2][ds2][2], 0,0,0);
        acc[ks2][ds2][3] = __builtin_amdgcn_mfma_f32_16x16x32_bf16(e2, bVh[ds2], acc[ks2][ds2][3], 0,0,0);
        acc[ks2][ds2][0] = __builtin_amdgcn_mfma_f32_16x16x32_bf16(e0, bKl[ds2], acc[ks2][ds2][0], 0,0,0);
        acc[ks2][ds2][1] = __builtin_amdgcn_mfma_f32_16x16x32_bf16(e2, bKl[ds2], acc[ks2][ds2][1], 0,0,0);
        acc[ks2][ds2][0] = __builtin_amdgcn_mfma_f32_16x16x32_bf16(e1, bKh[ds2], acc[ks2][ds2][0], 0,0,0);
        acc[ks2][ds2][1] = __builtin_amdgcn_mfma_f32_16x16x32_bf16(e3, bKh[ds2], acc[ks2][ds2][1], 0,0,0);
      }
    }
  };

  const int nch = part/32;           // 32 for N=8192, NSPLIT=8 (even)
  // prologue: fill buf0 (chunk 0); prefetch rfrac for chunk 1 into rfA
  stage(0, abase);
  {
    f4 r0[4]; rfload(r0, abase); egen_from(0, r0);
  }
  f4 rfA[4], rfB[4];
  rfload(rfA, abase + (nch > 1 ? 32 : 0));
  __syncthreads();
  for(int ch=0; ch<nch; ch+=2){
    { // even body: compute chunk ch (buf0); prepare chunk ch+1 (buf1)
      if(ch+1 < nch) stage(1, abase + (ch+1)*32);
      rfload(rfB, abase + min(ch+2, nch-1)*32);   // for egen(ch+2) next body
      mfma_body(0);
      if(ch+1 < nch) egen_from(1, rfA);
      __syncthreads();
    }
    { // odd body: compute chunk ch+1 (buf1); prepare chunk ch+2 (buf0)
      if(ch+2 < nch) stage(0, abase + (ch+2)*32);
      rfload(rfA, abase + min(ch+3, nch-1)*32);   // for egen(ch+3) next body
      mfma_body(1);
      if(ch+2 < nch) egen_from(0, rfB);
      __syncthreads();
    }
  }
  // epilogue: C/D layout col=lane&15 (d), row=(lane>>4)*4+reg (k)
  size_t M = (size_t)K*D128;
  #pragma unroll
  for(int ks2=0; ks2<2; ks2++){
    #pragma unroll
    for(int ds2=0; ds2<2; ds2++){
      #pragma unroll
      for(int reg=0; reg<4; reg++){
        int k = k0 + kbase + ks2*16 + g*4 + reg;
        if(k < K){
          int d = dbase + ds2*16 + l15;
          size_t base = (size_t)k*D128 + d;
          atomicAdd(&pot4[base],       acc[ks2][ds2][0][reg]);
          atomicAdd(&pot4[base + M],   acc[ks2][ds2][1][reg]);
          atomicAdd(&pot4[base + 2*M], acc[ks2][ds2][2][reg]);
          atomicAdd(&pot4[base + 3*M], acc[ks2][ds2][3][reg]);
        }
      }
    }
  }
}

// Emit |k_pot| (fp32 exact + bf16 swizzled) and Re/Im(v_pot); zero padding rows.
__global__ __launch_bounds__(256) void k_merge(const float* __restrict__ pot4,
    float* __restrict__ kabs, unsigned short* __restrict__ kabs_swz,
    float* __restrict__ vcm, float* __restrict__ vsm, int K, int KPAD){
  size_t M = (size_t)K*D128;
  size_t idx = (size_t)blockIdx.x*256 + threadIdx.x;
  if(idx >= (size_t)KPAD*D128) return;
  int k = (int)(idx >> 7), d = (int)(idx & 127);
  size_t sw = (size_t)k*D128 + ((((d>>3) ^ (k&7))<<3) | (d&7));
  if(idx < M){
    float kc = pot4[idx], ks_ = pot4[M+idx], vc = pot4[2*M+idx], vs = pot4[3*M+idx];
    float ab = sqrtf(fmaf(kc,kc, ks_*ks_));
    kabs[idx] = ab;
    vcm[idx] = vc; vsm[idx] = vs;
    kabs_swz[sw] = f2bu(ab);
  } else {
    kabs_swz[sw] = 0;
  }
}

// Screen GEMM via bf16 MFMA: aw[n,k] = sum_d |q|*|k_pot|.
// Block: 32 n-rows x 128 k. 4 waves, wave w owns k-block [w*32,+32).
// Emits per (row, 128-k tile) the top-8 entries within 21 of the tile max.
__global__ __launch_bounds__(256) void k_screen(
    const unsigned short* __restrict__ qa_bf, const unsigned short* __restrict__ kabs_swz,
    int* __restrict__ tk, float* __restrict__ taw, int N, int K, int NT){
  const int tid = threadIdx.x;
  const int w = tid >> 6, l = tid & 63, l15 = l & 15, g = l >> 4;
  const int n0 = blockIdx.x*SNR;
  const int ty = blockIdx.y;
  const int k0 = ty*SKT;
  __shared__ unsigned short Kb[SKT][D128];
  __shared__ unsigned short Qa[SNR][D128];
  __shared__ int cnt[SNR];
  __shared__ unsigned mx[SNR];
  if(tid < SNR){ cnt[tid] = 0; mx[tid] = 0u; }
  {
    int row = tid >> 3, s = tid & 7;
    size_t o = ((size_t)(n0+row)*NT + ty)*TOPS + s;
    taw[o] = -1e30f; tk[o] = -1;
  }
  #pragma unroll
  for(int j=0;j<8;j++){
    int sbase = w*512 + j*64;
    GLDS16(kabs_swz + (size_t)k0*D128 + (size_t)(sbase + l)*8,
           ((unsigned short*)Kb) + (size_t)sbase*8);
  }
  #pragma unroll
  for(int j=0;j<2;j++){
    int sbase = w*128 + j*64;
    GLDS16(qa_bf + (size_t)n0*D128 + (size_t)(sbase + l)*8,
           ((unsigned short*)Qa) + (size_t)sbase*8);
  }
  __syncthreads();
  f32x4 acc[2][2];   // [ksub][nsub]
  #pragma unroll
  for(int i=0;i<2;i++)
    #pragma unroll
    for(int j=0;j<2;j++)
      acc[i][j] = (f32x4){0.f,0.f,0.f,0.f};
  const int sz = l15 & 7;
  #pragma unroll
  for(int ds=0; ds<4; ds++){
    int c = (((ds*4 + g) ^ sz))*8;
    short8v a0 = *(const short8v*)&Kb[w*32 + l15][c];
    short8v a1 = *(const short8v*)&Kb[w*32 + 16 + l15][c];
    short8v b0 = *(const short8v*)&Qa[l15][c];
    short8v b1 = *(const short8v*)&Qa[16 + l15][c];
    acc[0][0] = __builtin_amdgcn_mfma_f32_16x16x32_bf16(a0, b0, acc[0][0], 0,0,0);
    acc[0][1] = __builtin_amdgcn_mfma_f32_16x16x32_bf16(a0, b1, acc[0][1], 0,0,0);
    acc[1][0] = __builtin_amdgcn_mfma_f32_16x16x32_bf16(a1, b0, acc[1][0], 0,0,0);
    acc[1][1] = __builtin_amdgcn_mfma_f32_16x16x32_bf16(a1, b1, acc[1][1], 0,0,0);
  }
  // per-n tile max; clamp to >=0 so padding can never win (uint order == float order for >=0)
  #pragma unroll
  for(int jn=0; jn<2; jn++){
    float m4 = 0.f;
    #pragma unroll
    for(int ks=0; ks<2; ks++)
      #pragma unroll
      for(int r=0; r<4; r++)
        m4 = fmaxf(m4, acc[ks][jn][r]);
    atomicMax(&mx[jn*16 + l15], __float_as_uint(m4));
  }
  __syncthreads();
  #pragma unroll
  for(int jn=0; jn<2; jn++){
    int n = jn*16 + l15;
    float thr = __uint_as_float(mx[n]) - 21.0f;
    #pragma unroll
    for(int ks=0; ks<2; ks++){
      #pragma unroll
      for(int r=0; r<4; r++){
        int k = k0 + w*32 + ks*16 + g*4 + r;
        float aw = acc[ks][jn][r];
        if(k < K && aw >= thr){
          int s = atomicAdd(&cnt[n], 1);
          if(s < TOPS){
            size_t o = ((size_t)(n0+n)*NT + ty)*TOPS + s;
            taw[o] = aw; tk[o] = k;
          }
        }
      }
    }
  }
}

// Per row: global max over candidates, exact fp32 logit recompute for survivors,
// softmax, and output accumulation from only those k's.
__global__ __launch_bounds__(256) void k_final(const float* __restrict__ q,
    const float* __restrict__ kabs, const float* __restrict__ vcm,
    const float* __restrict__ vsm, const float* __restrict__ rfrac,
    const int* __restrict__ kinv, const int* __restrict__ tk,
    const float* __restrict__ taw, float* __restrict__ out, int N, int K, int NT){
  const int rb = threadIdx.x >> 2;
  const int j  = threadIdx.x & 3;
  const int row = blockIdx.x*64 + rb;
  if(row >= N) return;
  const int NE = NT*TOPS;
  const float* trow = taw + (size_t)row*NE;
  const int*   krow = tk  + (size_t)row*NE;
  float m = -1e30f;
  for(int i=j; i<NE; i+=4) m = fmaxf(m, trow[i]);
  m = fmaxf(m, __shfl_xor(m,1)); m = fmaxf(m, __shfl_xor(m,2));
  __shared__ int lk[64][FCAP];
  __shared__ int lcnt[64];
  if(j==0) lcnt[rb] = 0;
  __syncthreads();
  for(int i=j; i<NE; i+=4){
    float aw = trow[i];
    if(aw >= m - 24.0f){
      int s = atomicAdd(&lcnt[rb], 1);
      if(s < FCAP) lk[rb][s] = krow[i];
    }
  }
  __syncthreads();
  int cn = min(lcnt[rb], FCAP);
  const float* qrow = q + (size_t)row*D128;
  float paw[FCAP];
  for(int e=0; e<cn; e++){
    int k = lk[rb][e];
    const float* ar = kabs + (size_t)k*D128;
    float p = 0.f;
    #pragma unroll
    for(int d=0; d<32; d+=4){
      int dd = j*32 + d;
      f4 qv = *(const f4*)(qrow+dd); f4 av = *(const f4*)(ar+dd);
      p = fmaf(fabsf(qv.x), av.x, p); p = fmaf(fabsf(qv.y), av.y, p);
      p = fmaf(fabsf(qv.z), av.z, p); p = fmaf(fabsf(qv.w), av.w, p);
    }
    p += __shfl_xor(p,1); p += __shfl_xor(p,2);
    paw[e] = p;
  }
  float m2 = -1e30f;
  for(int e=0;e<cn;e++) m2 = fmaxf(m2, paw[e]);
  float w[FCAP]; float Z = 0.f;
  for(int e=0;e<cn;e++){ w[e] = expf(paw[e]-m2); Z += w[e]; }
  float o[32];
  #pragma unroll
  for(int t=0;t<32;t++) o[t]=0.f;
  f4 rf = *(const f4*)(rfrac + (size_t)row*4);
  for(int e=0;e<cn;e++){
    float wn = w[e]/Z;
    if(wn < 1e-7f) continue;
    int k = lk[rb][e];
    float t = __builtin_amdgcn_fractf(rf.x*(float)kinv[k*3] + rf.y*(float)kinv[k*3+1] + rf.z*(float)kinv[k*3+2]);
    float si = __builtin_amdgcn_sinf(t), ci = __builtin_amdgcn_cosf(t);
    float wc = wn*ci, wsn = wn*si;
    const float* vcr = vcm + (size_t)k*D128 + j*32;
    const float* vsr = vsm + (size_t)k*D128 + j*32;
    #pragma unroll
    for(int d=0; d<32; d+=4){
      f4 a2 = *(const f4*)(vcr+d); f4 b2 = *(const f4*)(vsr+d);
      o[d]   = fmaf(wc, a2.x, fmaf(wsn, b2.x, o[d]));
      o[d+1] = fmaf(wc, a2.y, fmaf(wsn, b2.y, o[d+1]));
      o[d+2] = fmaf(wc, a2.z, fmaf(wsn, b2.z, o[d+2]));
      o[d+3] = fmaf(wc, a2.w, fmaf(wsn, b2.w, o[d+3]));
    }
  }
  float* orow = out + (size_t)row*D128 + j*32;
  #pragma unroll
  for(int d=0; d<32; d+=4)
    *(f4*)(orow+d) = make_float4(o[d], o[d+1], o[d+2], o[d+3]);
}

extern "C" void kernel_launch(void* const* d_in, const int* in_sizes, int n_in,
                              void* d_out, int out_size, void* d_ws, size_t ws_size,
                              hipStream_t stream){
  const float* q    = (const float*)d_in[0];
  const float* kvec = (const float*)d_in[1];
  const float* vvec = (const float*)d_in[2];
  const float* pos  = (const float*)d_in[3];
  const float* cell = (const float*)d_in[4];
  const int*   kfwd = (const int*)d_in[6];
  const int*   kinv = (const int*)d_in[7];
  const int N = in_sizes[3]/3;
  const int K = in_sizes[6]/3;
  const int NT = (K + SKT - 1)/SKT;
  const int KPAD = NT*SKT;
  const int KTILES = (K + KT - 1)/KT;

  float* ws = (float*)d_ws;
  size_t o = 0;
  float* rfrac    = ws + o; o += (size_t)N*4;
  float* pot4     = ws + o; o += (size_t)4*K*D128;
  float* kabs     = ws + o; o += (size_t)K*D128;
  float* vcm      = ws + o; o += (size_t)K*D128;
  float* vsm      = ws + o; o += (size_t)K*D128;
  unsigned short* kabs_swz = (unsigned short*)(ws + o); o += (size_t)KPAD*D128/2 + 4;
  unsigned short* qa_bf    = (unsigned short*)(ws + o); o += (size_t)N*D128/2 + 4;
  float* taw      = ws + o; o += (size_t)N*NT*TOPS;
  int*   tk       = (int*)(ws + o); o += (size_t)N*NT*TOPS;
  unsigned short* kvhT = (unsigned short*)(ws + o); o += (size_t)D128*N/2;
  unsigned short* kvlT = (unsigned short*)(ws + o); o += (size_t)D128*N/2;
  unsigned short* vvhT = (unsigned short*)(ws + o); o += (size_t)D128*N/2;
  float* out = (float*)d_out;

  k_zero<<<dim3(1024), dim3(256), 0, stream>>>(pot4, 4*K*D128);
  k_cvt<<<dim3(N/32), dim3(256), 0, stream>>>(pos, cell, rfrac, q, kvec, vvec,
      kvhT, kvlT, vvhT, qa_bf, N);
  k_pot_mfma<<<dim3(KTILES, NSPLIT), dim3(512), 0, stream>>>(
      kvhT, kvlT, vvhT, rfrac, kfwd, pot4, N, K);
  k_merge<<<dim3((KPAD*D128 + 255)/256), dim3(256), 0, stream>>>(
      pot4, kabs, kabs_swz, vcm, vsm, K, KPAD);
  k_screen<<<dim3(N/SNR, NT), dim3(256), 0, stream>>>(qa_bf, kabs_swz, tk, taw, N, K, NT);
  k_final<<<dim3((N+63)/64), dim3(256), 0, stream>>>(
      q, kabs, vcm, vsm, rfrac, kinv, tk, taw, out, N, K, NT);
}

// Round 11
// 242.580 us; speedup vs baseline: 1.0957x; 1.0957x over previous
//
#include <hip/hip_runtime.h>
#include <hip/hip_bf16.h>

#define D128 128
#define NSPLIT 8
#define KT 64
#define SNR 64
#define SKT 128
#define TOPS 8
#define FCAP 16

typedef float4 f4;
typedef __attribute__((ext_vector_type(8))) short short8v;
typedef __attribute__((ext_vector_type(4))) float f32x4;

__device__ __forceinline__ unsigned short f2bu(float x){
  __hip_bfloat16 h = __float2bfloat16(x);
  return *(unsigned short*)&h;
}
__device__ __forceinline__ float bu2f(unsigned short u){
  return __uint_as_float(((unsigned)u) << 16);
}

#define GLDS16(gp, lp) __builtin_amdgcn_global_load_lds( \
    (const __attribute__((address_space(1))) unsigned int*)(const void*)(gp), \
    (__attribute__((address_space(3))) unsigned int*)(lp), 16, 0, 0)

// Fused: zero pot4 (ws poisoned 0xAA each launch); rfrac = pos/box; transpose +
// bf16-split k_vector/v_vector into [d][atom]; |q| bf16 with chunk-XOR swizzle.
__global__ __launch_bounds__(256) void k_cvt(const float* __restrict__ pos,
    const float* __restrict__ cell, float* __restrict__ rfrac,
    const float* __restrict__ q, const float* __restrict__ kvec,
    const float* __restrict__ vvec, unsigned short* __restrict__ kvhT,
    unsigned short* __restrict__ kvlT, unsigned short* __restrict__ vvhT,
    unsigned short* __restrict__ qa_bf, float* __restrict__ pot4,
    int pot4_total, int N){
  __shared__ float sk[32][132], sv[32][132];
  const int tid = threadIdx.x;
  const int c0 = blockIdx.x*32;
  // zero pot4, grid-stride (k_pot_mfma launches after this kernel completes)
  {
    int i = blockIdx.x*256 + tid;
    int stride = gridDim.x*256;
    for(; i < pot4_total; i += stride) pot4[i] = 0.f;
  }
  if(tid < 32){
    int i = c0 + tid;
    float bx = cell[0], by = cell[4], bz = cell[8];
    f4 r; r.x = pos[i*3+0]/bx; r.y = pos[i*3+1]/by; r.z = pos[i*3+2]/bz; r.w = 0.f;
    ((f4*)rfrac)[i] = r;
  }
  #pragma unroll
  for(int i=0;i<2;i++){
    int idx = tid + i*256;            // 512 tasks: 32 rows x 16 chunks
    int row = idx >> 4, c = idx & 15;
    const float* src = q + (size_t)(c0+row)*D128 + c*8;
    f4 v0 = *(const f4*)src, v1 = *(const f4*)(src+4);
    uint4 o;
    o.x = (unsigned)f2bu(fabsf(v0.x)) | ((unsigned)f2bu(fabsf(v0.y))<<16);
    o.y = (unsigned)f2bu(fabsf(v0.z)) | ((unsigned)f2bu(fabsf(v0.w))<<16);
    o.z = (unsigned)f2bu(fabsf(v1.x)) | ((unsigned)f2bu(fabsf(v1.y))<<16);
    o.w = (unsigned)f2bu(fabsf(v1.z)) | ((unsigned)f2bu(fabsf(v1.w))<<16);
    *(uint4*)(qa_bf + (size_t)(c0+row)*D128 + ((c ^ (row&7))<<3)) = o;
  }
  #pragma unroll
  for(int i=0;i<4;i++){
    int idx = tid + i*256;            // 1024 f4-loads: 32 atoms x 32 quads
    int a = idx >> 5, fq = idx & 31;
    f4 v = ((const f4*)(kvec + (size_t)(c0+a)*D128))[fq];
    *(f4*)&sk[a][fq*4] = v;
    f4 u = ((const f4*)(vvec + (size_t)(c0+a)*D128))[fq];
    *(f4*)&sv[a][fq*4] = u;
  }
  __syncthreads();
  #pragma unroll
  for(int i=0;i<4;i++){
    int idx = tid + i*256;            // 1024 quad-items: 128 d x 8 atom-quads
    int d = idx >> 3, aq = idx & 7;
    size_t ob = (size_t)d*N + c0 + aq*4;
    ushort4 h, l, vh;
    float x0 = sk[aq*4+0][d], x1 = sk[aq*4+1][d], x2 = sk[aq*4+2][d], x3 = sk[aq*4+3][d];
    h.x = f2bu(x0); h.y = f2bu(x1); h.z = f2bu(x2); h.w = f2bu(x3);
    l.x = f2bu(x0 - bu2f(h.x)); l.y = f2bu(x1 - bu2f(h.y));
    l.z = f2bu(x2 - bu2f(h.z)); l.w = f2bu(x3 - bu2f(h.w));
    vh.x = f2bu(sv[aq*4+0][d]); vh.y = f2bu(sv[aq*4+1][d]);
    vh.z = f2bu(sv[aq*4+2][d]); vh.w = f2bu(sv[aq*4+3][d]);
    *(ushort4*)(kvhT + ob) = h;
    *(ushort4*)(kvlT + ob) = l;
    *(ushort4*)(vvhT + ob) = vh;
  }
}

// MFMA structure factors (round-8 proven form). 512 threads / 8 waves =
// 2 k-waves x 4 d-waves; wave tile k32 x d32. Per chunk per wave: 6 Bl reads
// (cached across ksubs) + 8 Ae reads for 32 MFMAs. 2-phase, swizzled, hw trig.
__global__ __launch_bounds__(512) void k_pot_mfma(
    const unsigned short* __restrict__ kvhT, const unsigned short* __restrict__ kvlT,
    const unsigned short* __restrict__ vvhT, const float* __restrict__ rfrac,
    const int* __restrict__ kfwd, float* __restrict__ pot4, int N, int K){
  const int tid = threadIdx.x;
  const int k0 = blockIdx.x*KT;
  const int split = blockIdx.y;
  const int part = N/NSPLIT;
  const int abase = split*part;
  __shared__ unsigned short Ae[2][4][KT][32];    // 32 KB
  __shared__ unsigned short Bl[2][3][D128][32];  // 48 KB
  const int w = tid >> 6, l = tid & 63, l15 = l & 15, g = l >> 4;
  const int kbase = (w & 1)*32, dbase = (w >> 1)*32;
  const int ke = tid >> 3;           // 0..63 local k
  const int ae0 = (tid & 7)*4;       // atom base
  float kfx, kfy, kfz;
  {
    int kk = min(k0 + ke, K-1);
    kfx = (float)kfwd[3*kk]; kfy = (float)kfwd[3*kk+1]; kfz = (float)kfwd[3*kk+2];
  }
  f32x4 acc[2][2][4];   // [ksub][dsub][kc,ks,vc,vs]
  #pragma unroll
  for(int i=0;i<2;i++)
    #pragma unroll
    for(int j=0;j<2;j++)
      #pragma unroll
      for(int p=0;p<4;p++)
        acc[i][j][p] = (f32x4){0.f,0.f,0.f,0.f};
  const int csrcS = ((l & 3) ^ ((l >> 3) & 3))*8;     // staging source chunk (shorts)
  const int cA    = (g ^ ((l15 >> 1) & 3))*8;         // swizzled read chunk (shorts)

  auto stage = [&](int buf, int c0a){
    int rbase = w*16;
    size_t goff = (size_t)(rbase + (l >> 2))*N + c0a + csrcS;
    GLDS16(kvhT + goff, &Bl[buf][0][rbase][0]);
    GLDS16(kvlT + goff, &Bl[buf][1][rbase][0]);
    GLDS16(vvhT + goff, &Bl[buf][2][rbase][0]);
  };
  auto egen = [&](int buf, int c0a){
    unsigned ow0[2], ow1[2], ow2[2], ow3[2];
    #pragma unroll
    for(int jp=0; jp<2; jp++){
      f4 ra = ((const f4*)rfrac)[c0a + ae0 + jp*2];
      f4 rb = ((const f4*)rfrac)[c0a + ae0 + jp*2 + 1];
      float ta = __builtin_amdgcn_fractf(ra.x*kfx + ra.y*kfy + ra.z*kfz);
      float tb = __builtin_amdgcn_fractf(rb.x*kfx + rb.y*kfy + rb.z*kfz);
      float ca = __builtin_amdgcn_cosf(ta), sa = __builtin_amdgcn_sinf(ta);
      float cb = __builtin_amdgcn_cosf(tb), sb = __builtin_amdgcn_sinf(tb);
      unsigned cba = __float_as_uint(ca), cbb = __float_as_uint(cb);
      unsigned sba = __float_as_uint(sa), sbb = __float_as_uint(sb);
      ow0[jp] = (cba >> 16) | (cbb & 0xffff0000u);
      ow2[jp] = (sba >> 16) | (sbb & 0xffff0000u);
      float cla = ca - __uint_as_float(cba & 0xffff0000u);
      float clb = cb - __uint_as_float(cbb & 0xffff0000u);
      float sla = sa - __uint_as_float(sba & 0xffff0000u);
      float slb = sb - __uint_as_float(sbb & 0xffff0000u);
      ow1[jp] = (unsigned)f2bu(cla) | ((unsigned)f2bu(clb) << 16);
      ow3[jp] = (unsigned)f2bu(sla) | ((unsigned)f2bu(slb) << 16);
    }
    int cdst = ((((ae0 >> 3) ^ ((ke >> 1) & 3)) << 3) | (ae0 & 4));  // shorts
    *(uint2*)&Ae[buf][0][ke][cdst] = make_uint2(ow0[0], ow0[1]);
    *(uint2*)&Ae[buf][1][ke][cdst] = make_uint2(ow1[0], ow1[1]);
    *(uint2*)&Ae[buf][2][ke][cdst] = make_uint2(ow2[0], ow2[1]);
    *(uint2*)&Ae[buf][3][ke][cdst] = make_uint2(ow3[0], ow3[1]);
  };

  stage(0, abase); egen(0, abase);
  __syncthreads();
  const int nch = part/32;
  for(int ch=0; ch<nch; ch++){
    int cur = ch & 1;
    if(ch+1 < nch){ stage(cur^1, abase + (ch+1)*32); egen(cur^1, abase + (ch+1)*32); }
    short8v bKh[2], bKl[2], bVh[2];
    #pragma unroll
    for(int ds2=0; ds2<2; ds2++){
      int row = dbase + ds2*16 + l15;
      bKh[ds2] = *(const short8v*)&Bl[cur][0][row][cA];
      bKl[ds2] = *(const short8v*)&Bl[cur][1][row][cA];
      bVh[ds2] = *(const short8v*)&Bl[cur][2][row][cA];
    }
    #pragma unroll
    for(int ks2=0; ks2<2; ks2++){
      int krow = kbase + ks2*16 + l15;
      short8v e0 = *(const short8v*)&Ae[cur][0][krow][cA];
      short8v e1 = *(const short8v*)&Ae[cur][1][krow][cA];
      short8v e2 = *(const short8v*)&Ae[cur][2][krow][cA];
      short8v e3 = *(const short8v*)&Ae[cur][3][krow][cA];
      #pragma unroll
      for(int ds2=0; ds2<2; ds2++){
        acc[ks2][ds2][0] = __builtin_amdgcn_mfma_f32_16x16x32_bf16(e0, bKh[ds2], acc[ks2][ds2][0], 0,0,0);
        acc[ks2][ds2][1] = __builtin_amdgcn_mfma_f32_16x16x32_bf16(e2, bKh[ds2], acc[ks2][ds2][1], 0,0,0);
        acc[ks2][ds2][2] = __builtin_amdgcn_mfma_f32_16x16x32_bf16(e0, bVh[ds2], acc[ks2][ds2][2], 0,0,0);
        acc[ks2][ds2][3] = __builtin_amdgcn_mfma_f32_16x16x32_bf16(e2, bVh[ds2], acc[ks2][ds2][3], 0,0,0);
        acc[ks2][ds2][0] = __builtin_amdgcn_mfma_f32_16x16x32_bf16(e0, bKl[ds2], acc[ks2][ds2][0], 0,0,0);
        acc[ks2][ds2][1] = __builtin_amdgcn_mfma_f32_16x16x32_bf16(e2, bKl[ds2], acc[ks2][ds2][1], 0,0,0);
        acc[ks2][ds2][0] = __builtin_amdgcn_mfma_f32_16x16x32_bf16(e1, bKh[ds2], acc[ks2][ds2][0], 0,0,0);
        acc[ks2][ds2][1] = __builtin_amdgcn_mfma_f32_16x16x32_bf16(e3, bKh[ds2], acc[ks2][ds2][1], 0,0,0);
      }
    }
    __syncthreads();
  }
  // epilogue: C/D layout col=lane&15 (d), row=(lane>>4)*4+reg (k)
  size_t M = (size_t)K*D128;
  #pragma unroll
  for(int ks2=0; ks2<2; ks2++){
    #pragma unroll
    for(int ds2=0; ds2<2; ds2++){
      #pragma unroll
      for(int reg=0; reg<4; reg++){
        int k = k0 + kbase + ks2*16 + g*4 + reg;
        if(k < K){
          int d = dbase + ds2*16 + l15;
          size_t base = (size_t)k*D128 + d;
          atomicAdd(&pot4[base],       acc[ks2][ds2][0][reg]);
          atomicAdd(&pot4[base + M],   acc[ks2][ds2][1][reg]);
          atomicAdd(&pot4[base + 2*M], acc[ks2][ds2][2][reg]);
          atomicAdd(&pot4[base + 3*M], acc[ks2][ds2][3][reg]);
        }
      }
    }
  }
}

// Emit |k_pot| (fp32 exact + bf16 swizzled) and Re/Im(v_pot); zero padding rows.
__global__ __launch_bounds__(256) void k_merge(const float* __restrict__ pot4,
    float* __restrict__ kabs, unsigned short* __restrict__ kabs_swz,
    float* __restrict__ vcm, float* __restrict__ vsm, int K, int KPAD){
  size_t M = (size_t)K*D128;
  size_t idx = (size_t)blockIdx.x*256 + threadIdx.x;
  if(idx >= (size_t)KPAD*D128) return;
  int k = (int)(idx >> 7), d = (int)(idx & 127);
  size_t sw = (size_t)k*D128 + ((((d>>3) ^ (k&7))<<3) | (d&7));
  if(idx < M){
    float kc = pot4[idx], ks_ = pot4[M+idx], vc = pot4[2*M+idx], vs = pot4[3*M+idx];
    float ab = sqrtf(fmaf(kc,kc, ks_*ks_));
    kabs[idx] = ab;
    vcm[idx] = vc; vsm[idx] = vs;
    kabs_swz[sw] = f2bu(ab);
  } else {
    kabs_swz[sw] = 0;
  }
}

// Screen GEMM via bf16 MFMA: aw[n,k] = sum_d |q|*|k_pot|.
// Block: 64 n-rows x 128 k (SNR=64 halves Kb re-staging vs 32). 4 waves,
// wave w owns k-block [w*32,+32) x all 64 n. Top-8 within 21 of tile max.
__global__ __launch_bounds__(256) void k_screen(
    const unsigned short* __restrict__ qa_bf, const unsigned short* __restrict__ kabs_swz,
    int* __restrict__ tk, float* __restrict__ taw, int N, int K, int NT){
  const int tid = threadIdx.x;
  const int w = tid >> 6, l = tid & 63, l15 = l & 15, g = l >> 4;
  const int n0 = blockIdx.x*SNR;
  const int ty = blockIdx.y;
  const int k0 = ty*SKT;
  __shared__ unsigned short Kb[SKT][D128];   // 32 KB
  __shared__ unsigned short Qa[SNR][D128];   // 16 KB
  __shared__ int cnt[SNR];
  __shared__ unsigned mx[SNR];
  if(tid < SNR){ cnt[tid] = 0; mx[tid] = 0u; }
  #pragma unroll
  for(int i=0;i<2;i++){
    int idx = tid + i*256;
    int row = idx >> 3, s = idx & 7;
    size_t o = ((size_t)(n0+row)*NT + ty)*TOPS + s;
    taw[o] = -1e30f; tk[o] = -1;
  }
  #pragma unroll
  for(int j=0;j<8;j++){
    int sbase = w*512 + j*64;
    GLDS16(kabs_swz + (size_t)k0*D128 + (size_t)(sbase + l)*8,
           ((unsigned short*)Kb) + (size_t)sbase*8);
  }
  #pragma unroll
  for(int j=0;j<4;j++){
    int sbase = w*256 + j*64;
    GLDS16(qa_bf + (size_t)n0*D128 + (size_t)(sbase + l)*8,
           ((unsigned short*)Qa) + (size_t)sbase*8);
  }
  __syncthreads();
  f32x4 acc[2][4];   // [ksub][nsub]
  #pragma unroll
  for(int i=0;i<2;i++)
    #pragma unroll
    for(int j=0;j<4;j++)
      acc[i][j] = (f32x4){0.f,0.f,0.f,0.f};
  const int sz = l15 & 7;
  #pragma unroll
  for(int ds=0; ds<4; ds++){
    int c = (((ds*4 + g) ^ sz))*8;
    short8v a0 = *(const short8v*)&Kb[w*32 + l15][c];
    short8v a1 = *(const short8v*)&Kb[w*32 + 16 + l15][c];
    #pragma unroll
    for(int jn=0; jn<4; jn++){
      short8v b = *(const short8v*)&Qa[jn*16 + l15][c];
      acc[0][jn] = __builtin_amdgcn_mfma_f32_16x16x32_bf16(a0, b, acc[0][jn], 0,0,0);
      acc[1][jn] = __builtin_amdgcn_mfma_f32_16x16x32_bf16(a1, b, acc[1][jn], 0,0,0);
    }
  }
  // per-n tile max; clamp to >=0 so padding can never win (uint order == float order for >=0)
  #pragma unroll
  for(int jn=0; jn<4; jn++){
    float m4 = 0.f;
    #pragma unroll
    for(int ks=0; ks<2; ks++)
      #pragma unroll
      for(int r=0; r<4; r++)
        m4 = fmaxf(m4, acc[ks][jn][r]);
    atomicMax(&mx[jn*16 + l15], __float_as_uint(m4));
  }
  __syncthreads();
  #pragma unroll
  for(int jn=0; jn<4; jn++){
    int n = jn*16 + l15;
    float thr = __uint_as_float(mx[n]) - 21.0f;
    #pragma unroll
    for(int ks=0; ks<2; ks++){
      #pragma unroll
      for(int r=0; r<4; r++){
        int k = k0 + w*32 + ks*16 + g*4 + r;
        float aw = acc[ks][jn][r];
        if(k < K && aw >= thr){
          int s = atomicAdd(&cnt[n], 1);
          if(s < TOPS){
            size_t o = ((size_t)(n0+n)*NT + ty)*TOPS + s;
            taw[o] = aw; tk[o] = k;
          }
        }
      }
    }
  }
}

// Per row: global max over candidates, exact fp32 logit recompute for survivors,
// softmax, and output accumulation from only those k's.
__global__ __launch_bounds__(256) void k_final(const float* __restrict__ q,
    const float* __restrict__ kabs, const float* __restrict__ vcm,
    const float* __restrict__ vsm, const float* __restrict__ rfrac,
    const int* __restrict__ kinv, const int* __restrict__ tk,
    const float* __restrict__ taw, float* __restrict__ out, int N, int K, int NT){
  const int rb = threadIdx.x >> 2;
  const int j  = threadIdx.x & 3;
  const int row = blockIdx.x*64 + rb;
  if(row >= N) return;
  const int NE = NT*TOPS;
  const float* trow = taw + (size_t)row*NE;
  const int*   krow = tk  + (size_t)row*NE;
  float m = -1e30f;
  for(int i=j; i<NE; i+=4) m = fmaxf(m, trow[i]);
  m = fmaxf(m, __shfl_xor(m,1)); m = fmaxf(m, __shfl_xor(m,2));
  __shared__ int lk[64][FCAP];
  __shared__ int lcnt[64];
  if(j==0) lcnt[rb] = 0;
  __syncthreads();
  for(int i=j; i<NE; i+=4){
    float aw = trow[i];
    if(aw >= m - 24.0f){
      int s = atomicAdd(&lcnt[rb], 1);
      if(s < FCAP) lk[rb][s] = krow[i];
    }
  }
  __syncthreads();
  int cn = min(lcnt[rb], FCAP);
  const float* qrow = q + (size_t)row*D128;
  float paw[FCAP];
  for(int e=0; e<cn; e++){
    int k = lk[rb][e];
    const float* ar = kabs + (size_t)k*D128;
    float p = 0.f;
    #pragma unroll
    for(int d=0; d<32; d+=4){
      int dd = j*32 + d;
      f4 qv = *(const f4*)(qrow+dd); f4 av = *(const f4*)(ar+dd);
      p = fmaf(fabsf(qv.x), av.x, p); p = fmaf(fabsf(qv.y), av.y, p);
      p = fmaf(fabsf(qv.z), av.z, p); p = fmaf(fabsf(qv.w), av.w, p);
    }
    p += __shfl_xor(p,1); p += __shfl_xor(p,2);
    paw[e] = p;
  }
  float m2 = -1e30f;
  for(int e=0;e<cn;e++) m2 = fmaxf(m2, paw[e]);
  float w[FCAP]; float Z = 0.f;
  for(int e=0;e<cn;e++){ w[e] = expf(paw[e]-m2); Z += w[e]; }
  float o[32];
  #pragma unroll
  for(int t=0;t<32;t++) o[t]=0.f;
  f4 rf = *(const f4*)(rfrac + (size_t)row*4);
  for(int e=0;e<cn;e++){
    float wn = w[e]/Z;
    if(wn < 1e-7f) continue;
    int k = lk[rb][e];
    float t = __builtin_amdgcn_fractf(rf.x*(float)kinv[k*3] + rf.y*(float)kinv[k*3+1] + rf.z*(float)kinv[k*3+2]);
    float si = __builtin_amdgcn_sinf(t), ci = __builtin_amdgcn_cosf(t);
    float wc = wn*ci, wsn = wn*si;
    const float* vcr = vcm + (size_t)k*D128 + j*32;
    const float* vsr = vsm + (size_t)k*D128 + j*32;
    #pragma unroll
    for(int d=0; d<32; d+=4){
      f4 a2 = *(const f4*)(vcr+d); f4 b2 = *(const f4*)(vsr+d);
      o[d]   = fmaf(wc, a2.x, fmaf(wsn, b2.x, o[d]));
      o[d+1] = fmaf(wc, a2.y, fmaf(wsn, b2.y, o[d+1]));
      o[d+2] = fmaf(wc, a2.z, fmaf(wsn, b2.z, o[d+2]));
      o[d+3] = fmaf(wc, a2.w, fmaf(wsn, b2.w, o[d+3]));
    }
  }
  float* orow = out + (size_t)row*D128 + j*32;
  #pragma unroll
  for(int d=0; d<32; d+=4)
    *(f4*)(orow+d) = make_float4(o[d], o[d+1], o[d+2], o[d+3]);
}

extern "C" void kernel_launch(void* const* d_in, const int* in_sizes, int n_in,
                              void* d_out, int out_size, void* d_ws, size_t ws_size,
                              hipStream_t stream){
  const float* q    = (const float*)d_in[0];
  const float* kvec = (const float*)d_in[1];
  const float* vvec = (const float*)d_in[2];
  const float* pos  = (const float*)d_in[3];
  const float* cell = (const float*)d_in[4];
  const int*   kfwd = (const int*)d_in[6];
  const int*   kinv = (const int*)d_in[7];
  const int N = in_sizes[3]/3;
  const int K = in_sizes[6]/3;
  const int NT = (K + SKT - 1)/SKT;
  const int KPAD = NT*SKT;
  const int KTILES = (K + KT - 1)/KT;

  float* ws = (float*)d_ws;
  size_t o = 0;
  float* rfrac    = ws + o; o += (size_t)N*4;
  float* pot4     = ws + o; o += (size_t)4*K*D128;
  float* kabs     = ws + o; o += (size_t)K*D128;
  float* vcm      = ws + o; o += (size_t)K*D128;
  float* vsm      = ws + o; o += (size_t)K*D128;
  unsigned short* kabs_swz = (unsigned short*)(ws + o); o += (size_t)KPAD*D128/2 + 4;
  unsigned short* qa_bf    = (unsigned short*)(ws + o); o += (size_t)N*D128/2 + 4;
  float* taw      = ws + o; o += (size_t)N*NT*TOPS;
  int*   tk       = (int*)(ws + o); o += (size_t)N*NT*TOPS;
  unsigned short* kvhT = (unsigned short*)(ws + o); o += (size_t)D128*N/2;
  unsigned short* kvlT = (unsigned short*)(ws + o); o += (size_t)D128*N/2;
  unsigned short* vvhT = (unsigned short*)(ws + o); o += (size_t)D128*N/2;
  float* out = (float*)d_out;

  k_cvt<<<dim3(N/32), dim3(256), 0, stream>>>(pos, cell, rfrac, q, kvec, vvec,
      kvhT, kvlT, vvhT, qa_bf, pot4, 4*K*D128, N);
  k_pot_mfma<<<dim3(KTILES, NSPLIT), dim3(512), 0, stream>>>(
      kvhT, kvlT, vvhT, rfrac, kfwd, pot4, N, K);
  k_merge<<<dim3((KPAD*D128 + 255)/256), dim3(256), 0, stream>>>(
      pot4, kabs, kabs_swz, vcm, vsm, K, KPAD);
  k_screen<<<dim3(N/SNR, NT), dim3(256), 0, stream>>>(qa_bf, kabs_swz, tk, taw, N, K, NT);
  k_final<<<dim3((N+63)/64), dim3(256), 0, stream>>>(
      q, kabs, vcm, vsm, rfrac, kinv, tk, taw, out, N, K, NT);
}